// Round 7
// baseline (1946.006 us; speedup 1.0000x reference)
//
#include <hip/hip_runtime.h>
#include <cstdint>
#include <cmath>

#define BT 8192   // tokens
#define DD 1024   // model dim
#define HH 4096   // hidden dim
#define EE 8      // experts
#define MT2 72    // max 256-row m-tiles: 16384/256 + 7 partials, padded to 72

typedef __attribute__((ext_vector_type(8))) short short8;
typedef __attribute__((ext_vector_type(4))) float f32x4;
typedef unsigned short u16;
typedef unsigned int u32;

// round-to-nearest-even fp32 -> bf16 (inputs are finite; no NaN path needed)
__device__ __forceinline__ u16 f2bf(float f) {
    u32 u = __float_as_uint(f);
    u += 0x7FFFu + ((u >> 16) & 1u);
    return (u16)(u >> 16);
}

// async global->LDS, 16B per lane; LDS dest is wave-uniform base + lane*16
__device__ __forceinline__ void gld_lds16(const void* g, void* l) {
    __builtin_amdgcn_global_load_lds((__attribute__((address_space(1))) void*)g,
                                     (__attribute__((address_space(3))) void*)l,
                                     16, 0, 0);
}

// ---------------- fp32 -> bf16 bulk convert (8 elems/thread) ----------------
__global__ void cvt_kernel(const float* __restrict__ src, u16* __restrict__ dst, int n8) {
    int i = blockIdx.x * blockDim.x + threadIdx.x;
    if (i >= n8) return;
    size_t base = (size_t)i * 8;
    float4 a = *(const float4*)(src + base);
    float4 b = *(const float4*)(src + base + 4);
    uint4 o;
    o.x = (u32)f2bf(a.x) | ((u32)f2bf(a.y) << 16);
    o.y = (u32)f2bf(a.z) | ((u32)f2bf(a.w) << 16);
    o.z = (u32)f2bf(b.x) | ((u32)f2bf(b.y) << 16);
    o.w = (u32)f2bf(b.z) | ((u32)f2bf(b.w) << 16);
    *(uint4*)(dst + base) = o;
}

// ---------------- gating: fp64 logits, top-2, softmax, build lists ----------
__global__ void gating_kernel(const float* __restrict__ x, const float* __restrict__ wg,
                              float* __restrict__ gate_arr, int* __restrict__ list,
                              int* __restrict__ info,
                              int* __restrict__ counts, float* __restrict__ importance) {
    int wave = (blockIdx.x * blockDim.x + threadIdx.x) >> 6;  // one wave per token
    int lane = threadIdx.x & 63;
    if (wave >= BT) return;
    const float* xr = x + (size_t)wave * DD;
    double acc[EE];
#pragma unroll
    for (int e = 0; e < EE; ++e) acc[e] = 0.0;
#pragma unroll
    for (int c = 0; c < DD / 256; ++c) {    // float4-vectorized, fp64 accumulate
        const int i = c * 256 + lane * 4;
        float4 xv = *(const float4*)(xr + i);
        double x0 = xv.x, x1 = xv.y, x2 = xv.z, x3 = xv.w;
#pragma unroll
        for (int e = 0; e < EE; ++e) {
            float4 wv = *(const float4*)(wg + e * DD + i);
            acc[e] += x0 * (double)wv.x + x1 * (double)wv.y
                    + x2 * (double)wv.z + x3 * (double)wv.w;
        }
    }
#pragma unroll
    for (int e = 0; e < EE; ++e) {
        double v = acc[e];
        for (int off = 32; off; off >>= 1) v += __shfl_down(v, off, 64);
        acc[e] = v;  // lane 0 holds the sum
    }
    if (lane == 0) {
        int i0 = 0; double v0 = acc[0];
        for (int e = 1; e < EE; ++e) if (acc[e] > v0) { v0 = acc[e]; i0 = e; }
        int i1 = -1; double v1 = -1e300;
        for (int e = 0; e < EE; ++e) { if (e == i0) continue; if (acc[e] > v1) { v1 = acc[e]; i1 = e; } }
        double e1 = exp(v1 - v0);
        double s = 1.0 + e1;
        float g0 = (float)(1.0 / s);
        float g1 = (float)(e1 / s);
        gate_arr[2 * wave]     = g0;
        gate_arr[2 * wave + 1] = g1;
        atomicAdd(&importance[i0], g0);
        atomicAdd(&importance[i1], g1);
        int p0 = atomicAdd(&counts[i0], 1);
        list[i0 * BT + p0] = wave;                 // token id
        int p1 = atomicAdd(&counts[i1], 1);
        list[i1 * BT + p1] = wave;
        info[2 * wave]     = (i0 << 16) | p0;      // (expert, position-in-list)
        info[2 * wave + 1] = (i1 << 16) | p1;
    }
}

// loss = 0.01*(cv^2(importance)+cv^2(load)); exclusive scan; dense tile map --
__global__ void loss_kernel(const int* __restrict__ counts, const float* __restrict__ importance,
                            int* __restrict__ offs, float* __restrict__ out_loss,
                            int* __restrict__ tmap, int* __restrict__ ntiles) {
    if (threadIdx.x == 0 && blockIdx.x == 0) {
        double mi = 0, ml = 0;
        int off = 0;
        for (int e = 0; e < EE; e++) {
            offs[e] = off; off += counts[e];
            mi += (double)importance[e]; ml += (double)counts[e];
        }
        mi /= EE; ml /= EE;
        double vi = 0, vl = 0;
        for (int e = 0; e < EE; e++) {
            double di = (double)importance[e] - mi; vi += di * di;
            double dl = (double)counts[e] - ml;     vl += dl * dl;
        }
        vi /= (EE - 1); vl /= (EE - 1);
        double cv_i = vi / (mi * mi + 1e-10);
        double cv_l = vl / (ml * ml + 1e-10);
        *out_loss = (float)((cv_i + cv_l) * 0.01);
        // dense 256-row M-tile map shared by both GEMMs
        int ntl = 0;
        for (int e = 0; e < EE; e++)
            for (int t = 0; t < counts[e]; t += 256)
                tmap[ntl++] = (e << 20) | t;       // (expert, mbase-within-expert)
        *ntiles = ntl;                              // <= 71
    }
}

// ------- gather x token rows into packed expert-major bf16 layout -----------
__global__ void gather_x_kernel(const float* __restrict__ x, const int* __restrict__ list,
                                const int* __restrict__ counts, const int* __restrict__ offs,
                                u16* __restrict__ xg) {
    int r = blockIdx.x;   // packed row, 0..2*BT-1
    int e = 0;
#pragma unroll
    for (int i = 1; i < EE; ++i) if (r >= offs[i]) e = i;
    int m = r - offs[e];
    if (m >= counts[e]) return;  // defensive; sum of counts == 2*BT
    int token = list[e * BT + m];
    const float* src = x + (size_t)token * DD;
    u16* dst = xg + (size_t)r * DD;
    int i = threadIdx.x * 4;
    float4 a = *(const float4*)(src + i);
    uint2 o;
    o.x = (u32)f2bf(a.x) | ((u32)f2bf(a.y) << 16);
    o.y = (u32)f2bf(a.z) | ((u32)f2bf(a.w) << 16);
    *(uint2*)(dst + i) = o;
}

// ========== packed-row MFMA GEMM, 256x256, 8-phase + frag read-ahead ========
// Round-6 schedule (passed correctness) with ONE fix: __launch_bounds__(512,2)
// raises the compiler's VGPR cap from 128 to 256 (2 waves/EU -> 256 VGPR per
// m69's occupancy steps). Round 6's demand (~acc 64 + afr 64 + bfr 32 +
// addressing) exceeded the default 128 cap -> ~70-reg scratch spill; the
// counters showed it as WRITE_SIZE 65.5->167 MB and FETCH +200 MB. Occupancy
// is unaffected: 128 KiB LDS already limits to 1 block/CU = 2 waves/SIMD.
// Schedule (unchanged): B-frags cached per nh (B read once per K-tile),
// frag read-ahead one phase (afr ping-pong), counted vmcnt(2) at ph3/ph7
// tops, one barrier per phase (two at ph3/7). Ledger and slot liveness as
// audited in round 6's header comment.
template <int K, int NT, bool GELU, bool GATHER>
__global__ __launch_bounds__(512, 2) void moe_gemm(const u16* __restrict__ Asrc,
                                                const u16* __restrict__ Bsrc,
                                                const float* __restrict__ bias,
                                                const int* __restrict__ list,
                                                const int* __restrict__ counts,
                                                const int* __restrict__ offs,
                                                const int* __restrict__ tmap,
                                                const int* __restrict__ ntiles,
                                                u16* __restrict__ outB,
                                                float* __restrict__ outF) {
    constexpr int NXT = NT / 256;          // n-tiles: 16 (GEMM1) / 4 (GEMM2)
    constexpr int nwg = NXT * MT2;         // 1152 / 288, both %8 == 0
    constexpr int QW = nwg / 8;
    constexpr int ITERS = K / 128;         // 8 (GEMM1) / 32 (GEMM2), >= 2
    const int tid = threadIdx.x;
    const int lane = tid & 63;
    const int wv = tid >> 6;               // 0..7
    const int wqr = wv >> 2;               // 64-row strip within quadrant
    const int wqc = wv & 3;                // 32-col strip within quadrant
    const int kq = lane >> 4;
    const int rsub = lane & 15;
    const int rq = kq * 4;
    const int ks1 = tid >> 7;              // my staging k-slice (0..3)
    const int r128 = tid & 127;            // my staging row within a half

    // [dbuf][op A=0/B=1][half][chunk*8]; chunk c = kslice*128 + row (16B each)
    __shared__ u16 Ls[2][2][2][8192];      // 131072 B static LDS, exactly 128 KiB

    const int nw = *ntiles;

#define STAGE_A(db, h, T)                                                   \
    do {                                                                    \
        gld_lds16(aP##h + (T) * 64,      &Ls[db][0][h][tid * 8]);           \
        gld_lds16(aP##h + (T) * 64 + 32, &Ls[db][0][h][(tid + 512) * 8]);   \
    } while (0)
#define STAGE_B(db, h, T)                                                   \
    do {                                                                    \
        gld_lds16(bP##h + (T) * 64,      &Ls[db][1][h][tid * 8]);           \
        gld_lds16(bP##h + (T) * 64 + 32, &Ls[db][1][h][(tid + 512) * 8]);   \
    } while (0)
#define WAIT4 asm volatile("s_waitcnt vmcnt(4)" ::: "memory")
#define WAIT2 asm volatile("s_waitcnt vmcnt(2)" ::: "memory")
#define WAIT0 asm volatile("s_waitcnt vmcnt(0)" ::: "memory")
#define BAR __builtin_amdgcn_s_barrier()

#define READ_A(s, db, mh)                                                     \
    do {                                                                      \
        _Pragma("unroll") for (int kk = 0; kk < 2; kk++)                      \
        _Pragma("unroll") for (int mi = 0; mi < 4; mi++)                      \
            afr[s][mi][kk] = *(const short8*)&Ls[db][0][mh]                   \
                [((kk * 4 + kq) * 128 + wqr * 64 + mi * 16 + rsub) * 8];      \
    } while (0)
#define READ_B(nh, db)                                                        \
    do {                                                                      \
        _Pragma("unroll") for (int kk = 0; kk < 2; kk++)                      \
        _Pragma("unroll") for (int ni = 0; ni < 2; ni++)                      \
            bfr[nh][ni][kk] = *(const short8*)&Ls[db][1][nh]                  \
                [((kk * 4 + kq) * 128 + wqc * 32 + ni * 16 + rsub) * 8];      \
    } while (0)
#define MFMAQ(s, mh, nh)                                                      \
    do {                                                                      \
        __builtin_amdgcn_s_setprio(1);                                        \
        _Pragma("unroll") for (int mi = 0; mi < 4; mi++)                      \
        _Pragma("unroll") for (int ni = 0; ni < 2; ni++)                      \
        _Pragma("unroll") for (int kk = 0; kk < 2; kk++)                      \
            acc[mh][nh][mi][ni] = __builtin_amdgcn_mfma_f32_16x16x32_bf16(    \
                afr[s][mi][kk], bfr[nh][ni][kk], acc[mh][nh][mi][ni], 0, 0, 0);\
        __builtin_amdgcn_s_setprio(0);                                        \
    } while (0)

#pragma unroll 1
    for (int raw = blockIdx.x; raw < nwg; raw += 256) {
        const int wg = (raw & 7) * QW + (raw >> 3);  // bijective XCD swizzle
        const int nt = wg / MT2;
        const int mt = wg - nt * MT2;
        if (mt >= nw) continue;                      // pad tile (block-uniform)
        const int ent = tmap[mt];
        const int e = ent >> 20;
        const int mbase = ent & 0xFFFFF;
        const int mmax = counts[e] - mbase;          // valid rows (>=1)
        const int rowbase = offs[e] + mbase;
        const int nbase = nt * 256;

        // row indices: direct per-thread loads; they feed staging addresses,
        // so they retire before STAGE 0 issues.
        size_t arow0, arow1;
        if constexpr (GATHER) {
            arow0 = (size_t)list[e * BT + mbase + min(r128, mmax - 1)];
            arow1 = (size_t)list[e * BT + mbase + min(128 + r128, mmax - 1)];
        } else {
            arow0 = (size_t)(rowbase + min(r128, mmax - 1));
            arow1 = (size_t)(rowbase + min(128 + r128, mmax - 1));
        }
        const u16* aP0 = Asrc + arow0 * (size_t)K + ks1 * 8;
        const u16* aP1 = Asrc + arow1 * (size_t)K + ks1 * 8;
        const u16* bP0 = Bsrc + ((size_t)e * NT + nbase + r128) * (size_t)K + ks1 * 8;
        const u16* bP1 = bP0 + (size_t)128 * K;

        f32x4 acc[2][2][4][2] = {};   // [mh][nh][mi][ni]
        short8 afr[2][4][2];          // [set][mi][kk]  (set: (phase>>1)&1)
        short8 bfr[2][2][2];          // [nh][ni][kk]   (reloaded once per dbuf)

        // prologue: tile0 (4 halves) -> dbuf0; tile1 A0,B0 -> dbuf1 (12 loads)
        STAGE_A(0, 0, 0); STAGE_B(0, 0, 0); STAGE_A(0, 1, 0); STAGE_B(0, 1, 0);
        STAGE_A(1, 0, 1); STAGE_B(1, 0, 1);
        WAIT4;                                   // tile0's 8 loads landed
        BAR;
        READ_A(0, 0, 0);                         // frags for ph0: afr set0 (d0,mh0)
        READ_B(0, 0);                            // bfr nh0 (d0)

#pragma unroll 1
        for (int it = 0; it < ITERS - 1; ++it) {
            const int t = 2 * it;
            // ph0: quad(0,0) d0
            READ_B(1, 0);  STAGE_A(1, 1, t + 1);  MFMAQ(0, 0, 0);  BAR;
            // ph1: quad(0,1) d0
            READ_A(1, 0, 1);  STAGE_B(1, 1, t + 1);  MFMAQ(0, 0, 1);  BAR;
            // ph2: quad(1,0) d0
            STAGE_A(0, 0, t + 2);  MFMAQ(1, 1, 0);  BAR;
            // ph3: quad(1,1) d0 — gate dbuf1 (tile t+1), read its frags
            WAIT2;  BAR;
            READ_A(0, 1, 0);  READ_B(0, 1);
            STAGE_B(0, 0, t + 2);  MFMAQ(1, 1, 1);  BAR;
            // ph4: quad(0,0) d1
            READ_B(1, 1);  STAGE_A(0, 1, t + 2);  MFMAQ(0, 0, 0);  BAR;
            // ph5: quad(0,1) d1
            READ_A(1, 1, 1);  STAGE_B(0, 1, t + 2);  MFMAQ(0, 0, 1);  BAR;
            // ph6: quad(1,0) d1
            STAGE_A(1, 0, t + 3);  MFMAQ(1, 1, 0);  BAR;
            // ph7: quad(1,1) d1 — gate dbuf0 (tile t+2), read its frags
            WAIT2;  BAR;
            READ_A(0, 0, 0);  READ_B(0, 0);
            STAGE_B(1, 0, t + 3);  MFMAQ(1, 1, 1);  BAR;
        }
        {   // tail iter: tiles t (dbuf0), t+1 (dbuf1, last); no t+2
            const int t = 2 * (ITERS - 1);
            READ_B(1, 0);  STAGE_A(1, 1, t + 1);  MFMAQ(0, 0, 0);  BAR;   // ph0
            READ_A(1, 0, 1);  STAGE_B(1, 1, t + 1);  MFMAQ(0, 0, 1);  BAR;// ph1
            MFMAQ(1, 1, 0);  BAR;                                          // ph2
            WAIT0;  BAR;                                                    // ph3
            READ_A(0, 1, 0);  READ_B(0, 1);
            MFMAQ(1, 1, 1);  BAR;
            READ_B(1, 1);  MFMAQ(0, 0, 0);  BAR;                           // ph4
            READ_A(1, 1, 1);  MFMAQ(0, 0, 1);  BAR;                        // ph5
            MFMAQ(1, 1, 0);  BAR;                                          // ph6
            MFMAQ(1, 1, 1);  BAR;                                          // ph7
        }

        // epilogue: C/D layout col = lane&15, row = (lane>>4)*4 + reg [m89]
        float bvals[2][2];
#pragma unroll
        for (int nh = 0; nh < 2; nh++)
#pragma unroll
            for (int ni = 0; ni < 2; ni++)
                bvals[nh][ni] = bias[(size_t)e * NT + nbase + nh * 128 + wqc * 32 + ni * 16 + rsub];
#pragma unroll
        for (int mh = 0; mh < 2; mh++) {
#pragma unroll
            for (int mi = 0; mi < 4; mi++) {
#pragma unroll
                for (int r = 0; r < 4; r++) {
                    int m = mh * 128 + wqr * 64 + mi * 16 + rq + r;
                    if (m < mmax) {
                        size_t ro = (size_t)(rowbase + m);
#pragma unroll
                        for (int nh = 0; nh < 2; nh++) {
#pragma unroll
                            for (int ni = 0; ni < 2; ni++) {
                                int n = nbase + nh * 128 + wqc * 32 + ni * 16 + rsub;
                                float v = acc[mh][nh][mi][ni][r] + bvals[nh][ni];
                                if constexpr (GELU) {
                                    v = 0.5f * v * (1.0f + erff(v * 0.7071067811865476f));
                                    outB[ro * NT + n] = f2bf(v);
                                } else {
                                    outF[ro * NT + n] = v;
                                }
                            }
                        }
                    }
                }
            }
        }
        WAIT0;   // drain epilogue stores so next tile's counted vmcnt is exact
    }
#undef READ_A
#undef READ_B
#undef MFMAQ
#undef STAGE_A
#undef STAGE_B
#undef WAIT4
#undef WAIT2
#undef WAIT0
#undef BAR
}

// ---------------- softmax over D for both slots + weighted combine + log ----
__global__ void combine_kernel(const float* __restrict__ o, const float* __restrict__ gates,
                               const int* __restrict__ info, const int* __restrict__ offs,
                               float* __restrict__ y) {
    const int b = blockIdx.x;
    const int tid = threadIdx.x;
    const int lane = tid & 63, wv = tid >> 6;
    const int inf0 = info[2 * b], inf1 = info[2 * b + 1];
    const int r0i = offs[inf0 >> 16] + (inf0 & 0xffff);
    const int r1i = offs[inf1 >> 16] + (inf1 & 0xffff);
    const float* r0 = o + (size_t)r0i * DD;
    const float* r1 = o + (size_t)r1i * DD;
    float v0[4], v1[4];
#pragma unroll
    for (int j = 0; j < 4; j++) { v0[j] = r0[tid + 256 * j]; v1[j] = r1[tid + 256 * j]; }
    float m0 = fmaxf(fmaxf(v0[0], v0[1]), fmaxf(v0[2], v0[3]));
    float m1 = fmaxf(fmaxf(v1[0], v1[1]), fmaxf(v1[2], v1[3]));
#pragma unroll
    for (int off = 32; off; off >>= 1) {
        m0 = fmaxf(m0, __shfl_xor(m0, off, 64));
        m1 = fmaxf(m1, __shfl_xor(m1, off, 64));
    }
    __shared__ float sred[2][4];
    if (lane == 0) { sred[0][wv] = m0; sred[1][wv] = m1; }
    __syncthreads();
    m0 = fmaxf(fmaxf(sred[0][0], sred[0][1]), fmaxf(sred[0][2], sred[0][3]));
    m1 = fmaxf(fmaxf(sred[1][0], sred[1][1]), fmaxf(sred[1][2], sred[1][3]));
    float p0[4], p1[4], s0 = 0.f, s1 = 0.f;
#pragma unroll
    for (int j = 0; j < 4; j++) {
        p0[j] = expf(v0[j] - m0); s0 += p0[j];
        p1[j] = expf(v1[j] - m1); s1 += p1[j];
    }
#pragma unroll
    for (int off = 32; off; off >>= 1) {
        s0 += __shfl_xor(s0, off, 64);
        s1 += __shfl_xor(s1, off, 64);
    }
    __shared__ float sred2[2][4];
    if (lane == 0) { sred2[0][wv] = s0; sred2[1][wv] = s1; }
    __syncthreads();
    s0 = sred2[0][0] + sred2[0][1] + sred2[0][2] + sred2[0][3];
    s1 = sred2[1][0] + sred2[1][1] + sred2[1][2] + sred2[1][3];
    const float c0 = gates[2 * b] / s0;
    const float c1 = gates[2 * b + 1] / s1;
#pragma unroll
    for (int j = 0; j < 4; j++) {
        float c = p0[j] * c0 + p1[j] * c1;
        if (c == 0.f) c = 2.2204460492503131e-16f;  // np.finfo(float64).eps
        y[(size_t)b * DD + tid + 256 * j] = logf(c);
    }
}

extern "C" void kernel_launch(void* const* d_in, const int* in_sizes, int n_in,
                              void* d_out, int out_size, void* d_ws, size_t ws_size,
                              hipStream_t stream) {
    const float* x     = (const float*)d_in[0];
    const float* wgate = (const float*)d_in[1];
    const float* fc1w  = (const float*)d_in[2];
    const float* fc1b  = (const float*)d_in[3];
    const float* fc2w  = (const float*)d_in[4];
    const float* fc2b  = (const float*)d_in[5];
    float* out = (float*)d_out;

    char* ws = (char*)d_ws;
    const size_t MB = 1024 * 1024;
    // big layout (289 MiB): [0,64) w1b (later o fp32, exactly 64 MiB)
    //                       [64,128) w2b; [128,256) h bf16 packed; [256,288) xg; meta@288
    // small layout (273 MiB): [0,64) w1b/o; [64,128) w2b; [128,144) xb; [144,272) h; meta@272
    const bool big = ws_size >= 289 * MB;
    u16* w1b = (u16*)(ws);
    float* o = (float*)(ws);
    u16* w2b = (u16*)(ws + 64 * MB);
    u16* xb  = (u16*)(ws + 128 * MB);              // small path only
    u16* h   = (u16*)(ws + (big ? 128 : 144) * MB);
    u16* xg  = (u16*)(ws + 256 * MB);              // big path only
    char* meta = ws + (big ? 288 : 272) * MB;
    int* counts       = (int*)meta;                 // 32 B
    int* offs         = (int*)(meta + 32);          // 32 B
    float* importance = (float*)(meta + 64);        // 32 B
    int* ntiles       = (int*)(meta + 96);          // 4 B (written by loss_kernel)
    float* gate_arr   = (float*)(meta + 128);       // 64 KiB
    int* info         = (int*)(meta + 128 + 65536); // 64 KiB
    int* list         = (int*)(meta + 128 + 131072);// 256 KiB
    int* tmap         = (int*)(meta + 512 * 1024);  // 288 B

    hipMemsetAsync(meta, 0, 96, stream);  // counts + offs + importance
    cvt_kernel<<<(EE * HH * DD / 8 + 255) / 256, 256, 0, stream>>>(fc1w, w1b, EE * HH * DD / 8);
    cvt_kernel<<<(EE * DD * HH / 8 + 255) / 256, 256, 0, stream>>>(fc2w, w2b, EE * DD * HH / 8);
    gating_kernel<<<BT / 4, 256, 0, stream>>>(x, wgate, gate_arr, list, info, counts, importance);
    loss_kernel<<<1, 64, 0, stream>>>(counts, importance, offs, out + (size_t)BT * DD, tmap, ntiles);

    if (big) {
        gather_x_kernel<<<2 * BT, 256, 0, stream>>>(x, list, counts, offs, xg);
        moe_gemm<DD, HH, true, false><<<256, 512, 0, stream>>>(
            xg, w1b, fc1b, nullptr, counts, offs, tmap, ntiles, h, nullptr);
    } else {
        cvt_kernel<<<(BT * DD / 8 + 255) / 256, 256, 0, stream>>>(x, xb, BT * DD / 8);
        moe_gemm<DD, HH, true, true><<<256, 512, 0, stream>>>(
            xb, w1b, fc1b, list, counts, offs, tmap, ntiles, h, nullptr);
    }
    // pass B: o = h @ fc2_w^T + fc2_b ; A rows contiguous (packed), o packed.
    moe_gemm<HH, DD, false, false><<<256, 512, 0, stream>>>(
        h, w2b, fc2b, nullptr, counts, offs, tmap, ntiles, nullptr, o);
    combine_kernel<<<BT, 256, 0, stream>>>(o, gate_arr, info, offs, out);
}

// Round 8
// 1173.644 us; speedup vs baseline: 1.6581x; 1.6581x over previous
//
#include <hip/hip_runtime.h>
#include <cstdint>
#include <cmath>

#define BT 8192   // tokens
#define DD 1024   // model dim
#define HH 4096   // hidden dim
#define EE 8      // experts
#define MT2 72    // max 256-row m-tiles: 16384/256 + 7 partials, padded to 72

typedef __attribute__((ext_vector_type(8))) short short8;
typedef __attribute__((ext_vector_type(4))) float f32x4;
typedef unsigned short u16;
typedef unsigned int u32;

// round-to-nearest-even fp32 -> bf16 (inputs are finite; no NaN path needed)
__device__ __forceinline__ u16 f2bf(float f) {
    u32 u = __float_as_uint(f);
    u += 0x7FFFu + ((u >> 16) & 1u);
    return (u16)(u >> 16);
}

// async global->LDS, 16B per lane; LDS dest is wave-uniform base + lane*16
__device__ __forceinline__ void gld_lds16(const void* g, void* l) {
    __builtin_amdgcn_global_load_lds((__attribute__((address_space(1))) void*)g,
                                     (__attribute__((address_space(3))) void*)l,
                                     16, 0, 0);
}

// ---------------- fp32 -> bf16 bulk convert (8 elems/thread) ----------------
__global__ void cvt_kernel(const float* __restrict__ src, u16* __restrict__ dst, int n8) {
    int i = blockIdx.x * blockDim.x + threadIdx.x;
    if (i >= n8) return;
    size_t base = (size_t)i * 8;
    float4 a = *(const float4*)(src + base);
    float4 b = *(const float4*)(src + base + 4);
    uint4 o;
    o.x = (u32)f2bf(a.x) | ((u32)f2bf(a.y) << 16);
    o.y = (u32)f2bf(a.z) | ((u32)f2bf(a.w) << 16);
    o.z = (u32)f2bf(b.x) | ((u32)f2bf(b.y) << 16);
    o.w = (u32)f2bf(b.z) | ((u32)f2bf(b.w) << 16);
    *(uint4*)(dst + base) = o;
}

// ---------------- gating: fp64 logits, top-2, softmax, build lists ----------
__global__ void gating_kernel(const float* __restrict__ x, const float* __restrict__ wg,
                              float* __restrict__ gate_arr, int* __restrict__ list,
                              int* __restrict__ info,
                              int* __restrict__ counts, float* __restrict__ importance) {
    int wave = (blockIdx.x * blockDim.x + threadIdx.x) >> 6;  // one wave per token
    int lane = threadIdx.x & 63;
    if (wave >= BT) return;
    const float* xr = x + (size_t)wave * DD;
    double acc[EE];
#pragma unroll
    for (int e = 0; e < EE; ++e) acc[e] = 0.0;
#pragma unroll
    for (int c = 0; c < DD / 256; ++c) {    // float4-vectorized, fp64 accumulate
        const int i = c * 256 + lane * 4;
        float4 xv = *(const float4*)(xr + i);
        double x0 = xv.x, x1 = xv.y, x2 = xv.z, x3 = xv.w;
#pragma unroll
        for (int e = 0; e < EE; ++e) {
            float4 wv = *(const float4*)(wg + e * DD + i);
            acc[e] += x0 * (double)wv.x + x1 * (double)wv.y
                    + x2 * (double)wv.z + x3 * (double)wv.w;
        }
    }
#pragma unroll
    for (int e = 0; e < EE; ++e) {
        double v = acc[e];
        for (int off = 32; off; off >>= 1) v += __shfl_down(v, off, 64);
        acc[e] = v;  // lane 0 holds the sum
    }
    if (lane == 0) {
        int i0 = 0; double v0 = acc[0];
        for (int e = 1; e < EE; ++e) if (acc[e] > v0) { v0 = acc[e]; i0 = e; }
        int i1 = -1; double v1 = -1e300;
        for (int e = 0; e < EE; ++e) { if (e == i0) continue; if (acc[e] > v1) { v1 = acc[e]; i1 = e; } }
        double e1 = exp(v1 - v0);
        double s = 1.0 + e1;
        float g0 = (float)(1.0 / s);
        float g1 = (float)(e1 / s);
        gate_arr[2 * wave]     = g0;
        gate_arr[2 * wave + 1] = g1;
        atomicAdd(&importance[i0], g0);
        atomicAdd(&importance[i1], g1);
        int p0 = atomicAdd(&counts[i0], 1);
        list[i0 * BT + p0] = wave;                 // token id
        int p1 = atomicAdd(&counts[i1], 1);
        list[i1 * BT + p1] = wave;
        info[2 * wave]     = (i0 << 16) | p0;      // (expert, position-in-list)
        info[2 * wave + 1] = (i1 << 16) | p1;
    }
}

// loss = 0.01*(cv^2(importance)+cv^2(load)); exclusive scan; dense tile map --
__global__ void loss_kernel(const int* __restrict__ counts, const float* __restrict__ importance,
                            int* __restrict__ offs, float* __restrict__ out_loss,
                            int* __restrict__ tmap, int* __restrict__ ntiles) {
    if (threadIdx.x == 0 && blockIdx.x == 0) {
        double mi = 0, ml = 0;
        int off = 0;
        for (int e = 0; e < EE; e++) {
            offs[e] = off; off += counts[e];
            mi += (double)importance[e]; ml += (double)counts[e];
        }
        mi /= EE; ml /= EE;
        double vi = 0, vl = 0;
        for (int e = 0; e < EE; e++) {
            double di = (double)importance[e] - mi; vi += di * di;
            double dl = (double)counts[e] - ml;     vl += dl * dl;
        }
        vi /= (EE - 1); vl /= (EE - 1);
        double cv_i = vi / (mi * mi + 1e-10);
        double cv_l = vl / (ml * ml + 1e-10);
        *out_loss = (float)((cv_i + cv_l) * 0.01);
        // dense 256-row M-tile map shared by both GEMMs
        int ntl = 0;
        for (int e = 0; e < EE; e++)
            for (int t = 0; t < counts[e]; t += 256)
                tmap[ntl++] = (e << 20) | t;       // (expert, mbase-within-expert)
        *ntiles = ntl;                              // <= 71
    }
}

// ------- gather x token rows into packed expert-major bf16 layout -----------
__global__ void gather_x_kernel(const float* __restrict__ x, const int* __restrict__ list,
                                const int* __restrict__ counts, const int* __restrict__ offs,
                                u16* __restrict__ xg) {
    int r = blockIdx.x;   // packed row, 0..2*BT-1
    int e = 0;
#pragma unroll
    for (int i = 1; i < EE; ++i) if (r >= offs[i]) e = i;
    int m = r - offs[e];
    if (m >= counts[e]) return;  // defensive; sum of counts == 2*BT
    int token = list[e * BT + m];
    const float* src = x + (size_t)token * DD;
    u16* dst = xg + (size_t)r * DD;
    int i = threadIdx.x * 4;
    float4 a = *(const float4*)(src + i);
    uint2 o;
    o.x = (u32)f2bf(a.x) | ((u32)f2bf(a.y) << 16);
    o.y = (u32)f2bf(a.z) | ((u32)f2bf(a.w) << 16);
    *(uint2*)(dst + i) = o;
}

// ====== packed-row MFMA GEMM, 256x256, 8-phase counted-vmcnt + B-cache ======
// EXACT round-5 stage/wait skeleton (benched 310us GEMM2, race-audited):
// per 64-K dbuf group, 4 quadrant-phases; stages A1(t+1)@ph0 B1(t+1)@ph1
// A0(t+2)@ph2 B0(t+2)@ph3+WAIT4, A1(t+2)@ph4 B1(t+2)@ph5 A0(t+3)@ph6
// B0(t+3)@ph7+WAIT4; vmcnt ledger enter=4 -> 6,8,10,12 -> WAIT4 -> 4.
// ONE change vs round 5: B-fragments cached in bfr[2][..] — read at ph0/ph1
// (nh0/nh1 of the dbuf), REUSED at ph2/ph3. LDS frag traffic per 64-K tile
// drops 256->192 KB/block (the 8-wave floor: A x4 share + B x2 share).
// Register ledger (the r6/r7 lesson): 512thr = 8 waves = 2/SIMD floor ->
// 256 unified VGPR/wave. acc = 128 (AGPR); arch = afr 32 + bfr 32 +
// addressing ~40 ~= 110 < 128 -> no spill (r6's afr double-set +64 did not
// fit; dropped). Verify via WRITE_SIZE == 65.5 MB (no scratch traffic).
// B LDS-slot liveness with caching: d0B0 rd ph0 / restaged ph3; d0B1 rd ph1 /
// st ph5; d1B0 rd ph4 / st ph7; d1B1 rd ph5 / st ph1' — all >=2 barriers
// after last read. A slots identical to round 5.
template <int K, int NT, bool GELU, bool GATHER>
__global__ __launch_bounds__(512) void moe_gemm(const u16* __restrict__ Asrc,
                                                const u16* __restrict__ Bsrc,
                                                const float* __restrict__ bias,
                                                const int* __restrict__ list,
                                                const int* __restrict__ counts,
                                                const int* __restrict__ offs,
                                                const int* __restrict__ tmap,
                                                const int* __restrict__ ntiles,
                                                u16* __restrict__ outB,
                                                float* __restrict__ outF) {
    constexpr int NXT = NT / 256;          // n-tiles: 16 (GEMM1) / 4 (GEMM2)
    constexpr int nwg = NXT * MT2;         // 1152 / 288, both %8 == 0
    constexpr int QW = nwg / 8;
    constexpr int ITERS = K / 128;         // 8 (GEMM1) / 32 (GEMM2), >= 2
    const int tid = threadIdx.x;
    const int lane = tid & 63;
    const int wv = tid >> 6;               // 0..7
    const int wqr = wv >> 2;               // 64-row strip within quadrant
    const int wqc = wv & 3;                // 32-col strip within quadrant
    const int kq = lane >> 4;
    const int rsub = lane & 15;
    const int rq = kq * 4;
    const int ks1 = tid >> 7;              // my staging k-slice (0..3)
    const int r128 = tid & 127;            // my staging row within a half

    // [dbuf][op A=0/B=1][half][chunk*8]; chunk c = kslice*128 + row (16B each)
    __shared__ u16 Ls[2][2][2][8192];      // 131072 B static LDS, exactly 128 KiB

    const int nw = *ntiles;

#define STAGE_A(db, h, T)                                                   \
    do {                                                                    \
        gld_lds16(aP##h + (T) * 64,      &Ls[db][0][h][tid * 8]);           \
        gld_lds16(aP##h + (T) * 64 + 32, &Ls[db][0][h][(tid + 512) * 8]);   \
    } while (0)
#define STAGE_B(db, h, T)                                                   \
    do {                                                                    \
        gld_lds16(bP##h + (T) * 64,      &Ls[db][1][h][tid * 8]);           \
        gld_lds16(bP##h + (T) * 64 + 32, &Ls[db][1][h][(tid + 512) * 8]);   \
    } while (0)
#define WAIT4 asm volatile("s_waitcnt vmcnt(4)" ::: "memory")
#define WAIT0 asm volatile("s_waitcnt vmcnt(0)" ::: "memory")
#define BAR __builtin_amdgcn_s_barrier()

#define READ_A(db, mh)                                                        \
    do {                                                                      \
        _Pragma("unroll") for (int kk = 0; kk < 2; kk++)                      \
        _Pragma("unroll") for (int mi = 0; mi < 4; mi++)                      \
            afr[mi][kk] = *(const short8*)&Ls[db][0][mh]                      \
                [((kk * 4 + kq) * 128 + wqr * 64 + mi * 16 + rsub) * 8];      \
    } while (0)
#define READ_B(nh, db)                                                        \
    do {                                                                      \
        _Pragma("unroll") for (int kk = 0; kk < 2; kk++)                      \
        _Pragma("unroll") for (int ni = 0; ni < 2; ni++)                      \
            bfr[nh][ni][kk] = *(const short8*)&Ls[db][1][nh]                  \
                [((kk * 4 + kq) * 128 + wqc * 32 + ni * 16 + rsub) * 8];      \
    } while (0)
#define MFMAQ(mh, nh)                                                         \
    do {                                                                      \
        __builtin_amdgcn_s_setprio(1);                                        \
        _Pragma("unroll") for (int mi = 0; mi < 4; mi++)                      \
        _Pragma("unroll") for (int ni = 0; ni < 2; ni++)                      \
        _Pragma("unroll") for (int kk = 0; kk < 2; kk++)                      \
            acc[mh][nh][mi][ni] = __builtin_amdgcn_mfma_f32_16x16x32_bf16(    \
                afr[mi][kk], bfr[nh][ni][kk], acc[mh][nh][mi][ni], 0, 0, 0);  \
        __builtin_amdgcn_s_setprio(0);                                        \
    } while (0)

#pragma unroll 1
    for (int raw = blockIdx.x; raw < nwg; raw += 256) {
        const int wg = (raw & 7) * QW + (raw >> 3);  // bijective XCD swizzle
        const int nt = wg / MT2;
        const int mt = wg - nt * MT2;
        if (mt >= nw) continue;                      // pad tile (block-uniform)
        const int ent = tmap[mt];
        const int e = ent >> 20;
        const int mbase = ent & 0xFFFFF;
        const int mmax = counts[e] - mbase;          // valid rows (>=1)
        const int rowbase = offs[e] + mbase;
        const int nbase = nt * 256;

        // row indices: direct per-thread loads; they feed staging addresses,
        // so they retire before STAGE 0 issues.
        size_t arow0, arow1;
        if constexpr (GATHER) {
            arow0 = (size_t)list[e * BT + mbase + min(r128, mmax - 1)];
            arow1 = (size_t)list[e * BT + mbase + min(128 + r128, mmax - 1)];
        } else {
            arow0 = (size_t)(rowbase + min(r128, mmax - 1));
            arow1 = (size_t)(rowbase + min(128 + r128, mmax - 1));
        }
        const u16* aP0 = Asrc + arow0 * (size_t)K + ks1 * 8;
        const u16* aP1 = Asrc + arow1 * (size_t)K + ks1 * 8;
        const u16* bP0 = Bsrc + ((size_t)e * NT + nbase + r128) * (size_t)K + ks1 * 8;
        const u16* bP1 = bP0 + (size_t)128 * K;

        f32x4 acc[2][2][4][2] = {};   // [mh][nh][mi][ni] — 128 regs (AGPR)
        short8 afr[4][2];             // [mi][kk] — current (db,mh) A frags
        short8 bfr[2][2][2];          // [nh][ni][kk] — cached per dbuf

        // prologue: tile0 (4 halves) -> dbuf0; tile1 A0,B0 -> dbuf1 (12 loads)
        STAGE_A(0, 0, 0); STAGE_B(0, 0, 0); STAGE_A(0, 1, 0); STAGE_B(0, 1, 0);
        STAGE_A(1, 0, 1); STAGE_B(1, 0, 1);
        WAIT4;                                   // tile0's 8 loads landed
        BAR;

#pragma unroll 1
        for (int it = 0; it < ITERS - 1; ++it) {
            const int t = 2 * it;
            // ph0 quad(0,0) d0
            READ_A(0, 0); READ_B(0, 0); STAGE_A(1, 1, t + 1); MFMAQ(0, 0); BAR;
            // ph1 quad(0,1) d0
            READ_B(1, 0); STAGE_B(1, 1, t + 1); MFMAQ(0, 1); BAR;
            // ph2 quad(1,0) d0 (bfr[0] reused)
            READ_A(0, 1); STAGE_A(0, 0, t + 2); MFMAQ(1, 0); BAR;
            // ph3 quad(1,1) d0 (bfr[1] reused) — tile t+1 gated at bottom
            STAGE_B(0, 0, t + 2); MFMAQ(1, 1); WAIT4; BAR;
            // ph4 quad(0,0) d1
            READ_A(1, 0); READ_B(0, 1); STAGE_A(0, 1, t + 2); MFMAQ(0, 0); BAR;
            // ph5 quad(0,1) d1
            READ_B(1, 1); STAGE_B(0, 1, t + 2); MFMAQ(0, 1); BAR;
            // ph6 quad(1,0) d1
            READ_A(1, 1); STAGE_A(1, 0, t + 3); MFMAQ(1, 0); BAR;
            // ph7 quad(1,1) d1 — tile t+2 gated at bottom
            STAGE_B(1, 0, t + 3); MFMAQ(1, 1); WAIT4; BAR;
        }
        {   // tail iter: tiles t (dbuf0), t+1 (dbuf1, last); no t+2/t+3 stages
            const int t = 2 * (ITERS - 1);
            READ_A(0, 0); READ_B(0, 0); STAGE_A(1, 1, t + 1); MFMAQ(0, 0); BAR;
            READ_B(1, 0); STAGE_B(1, 1, t + 1); MFMAQ(0, 1); BAR;
            READ_A(0, 1); MFMAQ(1, 0); BAR;
            MFMAQ(1, 1); WAIT0; BAR;                 // tile t+1 fully landed
            READ_A(1, 0); READ_B(0, 1); MFMAQ(0, 0); BAR;
            READ_B(1, 1); MFMAQ(0, 1); BAR;
            READ_A(1, 1); MFMAQ(1, 0); BAR;
            MFMAQ(1, 1); BAR;
        }

        // epilogue: C/D layout col = lane&15, row = (lane>>4)*4 + reg [m89]
        float bvals[2][2];
#pragma unroll
        for (int nh = 0; nh < 2; nh++)
#pragma unroll
            for (int ni = 0; ni < 2; ni++)
                bvals[nh][ni] = bias[(size_t)e * NT + nbase + nh * 128 + wqc * 32 + ni * 16 + rsub];
#pragma unroll
        for (int mh = 0; mh < 2; mh++) {
#pragma unroll
            for (int mi = 0; mi < 4; mi++) {
#pragma unroll
                for (int r = 0; r < 4; r++) {
                    int m = mh * 128 + wqr * 64 + mi * 16 + rq + r;
                    if (m < mmax) {
                        size_t ro = (size_t)(rowbase + m);
#pragma unroll
                        for (int nh = 0; nh < 2; nh++) {
#pragma unroll
                            for (int ni = 0; ni < 2; ni++) {
                                int n = nbase + nh * 128 + wqc * 32 + ni * 16 + rsub;
                                float v = acc[mh][nh][mi][ni][r] + bvals[nh][ni];
                                if constexpr (GELU) {
                                    v = 0.5f * v * (1.0f + erff(v * 0.7071067811865476f));
                                    outB[ro * NT + n] = f2bf(v);
                                } else {
                                    outF[ro * NT + n] = v;
                                }
                            }
                        }
                    }
                }
            }
        }
        WAIT0;   // drain epilogue stores so next tile's counted vmcnt is exact
    }
#undef READ_A
#undef READ_B
#undef MFMAQ
#undef STAGE_A
#undef STAGE_B
#undef WAIT4
#undef WAIT0
#undef BAR
}

// ---------------- softmax over D for both slots + weighted combine + log ----
__global__ void combine_kernel(const float* __restrict__ o, const float* __restrict__ gates,
                               const int* __restrict__ info, const int* __restrict__ offs,
                               float* __restrict__ y) {
    const int b = blockIdx.x;
    const int tid = threadIdx.x;
    const int lane = tid & 63, wv = tid >> 6;
    const int inf0 = info[2 * b], inf1 = info[2 * b + 1];
    const int r0i = offs[inf0 >> 16] + (inf0 & 0xffff);
    const int r1i = offs[inf1 >> 16] + (inf1 & 0xffff);
    const float* r0 = o + (size_t)r0i * DD;
    const float* r1 = o + (size_t)r1i * DD;
    float v0[4], v1[4];
#pragma unroll
    for (int j = 0; j < 4; j++) { v0[j] = r0[tid + 256 * j]; v1[j] = r1[tid + 256 * j]; }
    float m0 = fmaxf(fmaxf(v0[0], v0[1]), fmaxf(v0[2], v0[3]));
    float m1 = fmaxf(fmaxf(v1[0], v1[1]), fmaxf(v1[2], v1[3]));
#pragma unroll
    for (int off = 32; off; off >>= 1) {
        m0 = fmaxf(m0, __shfl_xor(m0, off, 64));
        m1 = fmaxf(m1, __shfl_xor(m1, off, 64));
    }
    __shared__ float sred[2][4];
    if (lane == 0) { sred[0][wv] = m0; sred[1][wv] = m1; }
    __syncthreads();
    m0 = fmaxf(fmaxf(sred[0][0], sred[0][1]), fmaxf(sred[0][2], sred[0][3]));
    m1 = fmaxf(fmaxf(sred[1][0], sred[1][1]), fmaxf(sred[1][2], sred[1][3]));
    float p0[4], p1[4], s0 = 0.f, s1 = 0.f;
#pragma unroll
    for (int j = 0; j < 4; j++) {
        p0[j] = expf(v0[j] - m0); s0 += p0[j];
        p1[j] = expf(v1[j] - m1); s1 += p1[j];
    }
#pragma unroll
    for (int off = 32; off; off >>= 1) {
        s0 += __shfl_xor(s0, off, 64);
        s1 += __shfl_xor(s1, off, 64);
    }
    __shared__ float sred2[2][4];
    if (lane == 0) { sred2[0][wv] = s0; sred2[1][wv] = s1; }
    __syncthreads();
    s0 = sred2[0][0] + sred2[0][1] + sred2[0][2] + sred2[0][3];
    s1 = sred2[1][0] + sred2[1][1] + sred2[1][2] + sred2[1][3];
    const float c0 = gates[2 * b] / s0;
    const float c1 = gates[2 * b + 1] / s1;
#pragma unroll
    for (int j = 0; j < 4; j++) {
        float c = p0[j] * c0 + p1[j] * c1;
        if (c == 0.f) c = 2.2204460492503131e-16f;  // np.finfo(float64).eps
        y[(size_t)b * DD + tid + 256 * j] = logf(c);
    }
}

extern "C" void kernel_launch(void* const* d_in, const int* in_sizes, int n_in,
                              void* d_out, int out_size, void* d_ws, size_t ws_size,
                              hipStream_t stream) {
    const float* x     = (const float*)d_in[0];
    const float* wgate = (const float*)d_in[1];
    const float* fc1w  = (const float*)d_in[2];
    const float* fc1b  = (const float*)d_in[3];
    const float* fc2w  = (const float*)d_in[4];
    const float* fc2b  = (const float*)d_in[5];
    float* out = (float*)d_out;

    char* ws = (char*)d_ws;
    const size_t MB = 1024 * 1024;
    // big layout (289 MiB): [0,64) w1b (later o fp32, exactly 64 MiB)
    //                       [64,128) w2b; [128,256) h bf16 packed; [256,288) xg; meta@288
    // small layout (273 MiB): [0,64) w1b/o; [64,128) w2b; [128,144) xb; [144,272) h; meta@272
    const bool big = ws_size >= 289 * MB;
    u16* w1b = (u16*)(ws);
    float* o = (float*)(ws);
    u16* w2b = (u16*)(ws + 64 * MB);
    u16* xb  = (u16*)(ws + 128 * MB);              // small path only
    u16* h   = (u16*)(ws + (big ? 128 : 144) * MB);
    u16* xg  = (u16*)(ws + 256 * MB);              // big path only
    char* meta = ws + (big ? 288 : 272) * MB;
    int* counts       = (int*)meta;                 // 32 B
    int* offs         = (int*)(meta + 32);          // 32 B
    float* importance = (float*)(meta + 64);        // 32 B
    int* ntiles       = (int*)(meta + 96);          // 4 B (written by loss_kernel)
    float* gate_arr   = (float*)(meta + 128);       // 64 KiB
    int* info         = (int*)(meta + 128 + 65536); // 64 KiB
    int* list         = (int*)(meta + 128 + 131072);// 256 KiB
    int* tmap         = (int*)(meta + 512 * 1024);  // 288 B

    hipMemsetAsync(meta, 0, 96, stream);  // counts + offs + importance
    cvt_kernel<<<(EE * HH * DD / 8 + 255) / 256, 256, 0, stream>>>(fc1w, w1b, EE * HH * DD / 8);
    cvt_kernel<<<(EE * DD * HH / 8 + 255) / 256, 256, 0, stream>>>(fc2w, w2b, EE * DD * HH / 8);
    gating_kernel<<<BT / 4, 256, 0, stream>>>(x, wgate, gate_arr, list, info, counts, importance);
    loss_kernel<<<1, 64, 0, stream>>>(counts, importance, offs, out + (size_t)BT * DD, tmap, ntiles);

    if (big) {
        gather_x_kernel<<<2 * BT, 256, 0, stream>>>(x, list, counts, offs, xg);
        moe_gemm<DD, HH, true, false><<<256, 512, 0, stream>>>(
            xg, w1b, fc1b, nullptr, counts, offs, tmap, ntiles, h, nullptr);
    } else {
        cvt_kernel<<<(BT * DD / 8 + 255) / 256, 256, 0, stream>>>(x, xb, BT * DD / 8);
        moe_gemm<DD, HH, true, true><<<256, 512, 0, stream>>>(
            xb, w1b, fc1b, list, counts, offs, tmap, ntiles, h, nullptr);
    }
    // pass B: o = h @ fc2_w^T + fc2_b ; A rows contiguous (packed), o packed.
    moe_gemm<HH, DD, false, false><<<256, 512, 0, stream>>>(
        h, w2b, fc2b, nullptr, counts, offs, tmap, ntiles, nullptr, o);
    combine_kernel<<<BT, 256, 0, stream>>>(o, gate_arr, info, offs, out);
}